// Round 15
// baseline (309.050 us; speedup 1.0000x reference)
//
#include <hip/hip_runtime.h>
#include <hip/hip_bf16.h>
#include <stdint.h>

#define TSTEPS 4

typedef __bf16 bf16_t;
typedef __attribute__((ext_vector_type(8))) __bf16 bf16x8;
typedef __attribute__((ext_vector_type(16))) float f32x16;
typedef __attribute__((ext_vector_type(4))) unsigned short ushort4v;

union frag_u { bf16x8 v; uint32_t d[4]; unsigned short u[8]; };

// gfx9 s_waitcnt imm: vm [3:0]|[15:14]; exp [6:4]; lgkm [11:8].
#define WT_VM3_LG0  0x073   // vmcnt(3) lgkmcnt(0)
#define WT_VM3      0xF73   // vmcnt(3)
#define WT_LG0      0xC07F  // lgkmcnt(0), vm unbounded
#define WT_VM0_LG0  0x070   // full drain (tail)

// ---------------------------------------------------------------------------
// R31 = R28 ring-4 base + PRE-EXPANDED bf16 A in LDS (kills the in-loop
// v_perm expansion). R28 accounting: per SIMD per step MFMA 774 + VALU 484
// = 91% of the 1382-cyc wall -> combined-ISSUE-bound; VALU is dominated by
// 16 v_perm + frag_u shuffling per wave-step. Fix: producers emit A as
// bf16 0x3F00 (=0.5) packets; MFMA reads LDS-staged fragments directly.
// R17's bf16-A failed with REGISTER loads (2x VMEM-return bytes); via
// global_load_lds the cost is 2->3 VMEM ops/wave-step + 12KB slabs
// (ring-4 = 48KB -> 3 blocks/CU = measured residency anyway).
// B pre-doubled (2*hi/2*lo, exact exponent bump) so 0.5*(2w) = w bitwise
// (R19/R21/R22-proven). Fused mean-over-L in LAST epilogue kept.
// A layout: packet (m_blk*NKB + kb)*4096 B: [t][half][row0..31][16B],
//           8 bf16 per (t,half,row), value 0x0000 / 0x3F00.
// B-frag layout: packet ((n>>5)*NKB + (k>>4))*512 + ((n&31)+32*((k>>3)&1))*8
// + (k&7), bf16, value = 2*w_hi / 2*w_lo.
// ws: s1 (8MB) aliased into h1 (64MB): s1 fully consumed by GEMM1 before
// GEMM2 writes h1 (same-stream ordering) — R17-proven.
// ---------------------------------------------------------------------------

// ---------------------------------------------------------------------------
// Stage 1: input LIF encoder -> bf16 spike packets. C=128. XLA-exact LIF.
// ---------------------------------------------------------------------------
__global__ void spike_encode_bf16(const float* __restrict__ x,
                                  uint8_t* __restrict__ s1)
{
    const int C = 128;
    int tid = blockIdx.x * blockDim.x + threadIdx.x;  // 65536 = 256*8*32
    int row = tid & 31;
    int kb  = (tid >> 5) & 7;
    int m_blk = tid >> 8;
    int m = m_blk * 32 + row;
    const float* px = x + (size_t)m * C + kb * 16;
    float xv[16];
#pragma unroll
    for (int j = 0; j < 16; j += 4) {
        float4 t4 = *(const float4*)(px + j);
        xv[j] = t4.x; xv[j+1] = t4.y; xv[j+2] = t4.z; xv[j+3] = t4.w;
    }
    float v[16];
#pragma unroll
    for (int j = 0; j < 16; ++j) v[j] = 0.0f;
    uint8_t* pkt0 = s1 + (size_t)(m_blk * 8 + kb) * 4096;
#pragma unroll
    for (int t = 0; t < TSTEPS; ++t) {
        uint32_t m16 = 0u;
#pragma unroll
        for (int j = 0; j < 16; ++j) {
            float vv = __fadd_rn(v[j], __fmul_rn(__fsub_rn(xv[j], v[j]), 0.5f));
            bool sp = (vv >= 1.0f);
            m16 |= sp ? (1u << j) : 0u;
            v[j] = sp ? 0.0f : vv;
        }
        uint32_t d[8];
#pragma unroll
        for (int jj = 0; jj < 8; ++jj) {
            uint32_t x2 = (m16 >> (2 * jj)) & 3u;
            d[jj] = ((x2 | (x2 << 15)) & 0x00010001u) * 0x3F00u;
        }
        uint4 o0; o0.x = d[0]; o0.y = d[1]; o0.z = d[2]; o0.w = d[3];
        uint4 o1; o1.x = d[4]; o1.y = d[5]; o1.z = d[6]; o1.w = d[7];
        *(uint4*)(pkt0 + (size_t)t * 1024 + row * 16)       = o0;   // k0-7
        *(uint4*)(pkt0 + (size_t)t * 1024 + 512 + row * 16) = o1;   // k8-15
    }
}

// ---------------------------------------------------------------------------
// Weight prep: W [K][N] fp32 -> 2*hi / 2*lo bf16 split in B-frag layout.
// ---------------------------------------------------------------------------
__global__ void split_transpose_all(const float* __restrict__ enc_W,
                                    const float* __restrict__ W_cells,
                                    bf16_t* __restrict__ W1h, bf16_t* __restrict__ W1l,
                                    bf16_t* __restrict__ W2h, bf16_t* __restrict__ W2l,
                                    bf16_t* __restrict__ W3h, bf16_t* __restrict__ W3l)
{
    const int N = 1024;
    const float* W;
    bf16_t *hi, *lo;
    int K;
    if (blockIdx.z == 0) {
        if (blockIdx.x >= 4) return;
        W = enc_W; hi = W1h; lo = W1l; K = 128;
    } else if (blockIdx.z == 1) {
        W = W_cells; hi = W2h; lo = W2l; K = 1024;
    } else {
        W = W_cells + (size_t)1024 * 1024; hi = W3h; lo = W3l; K = 1024;
    }
    const int NKB = K >> 4;
    __shared__ float tile[32][33];
    int k0 = blockIdx.x * 32, n0 = blockIdx.y * 32;
    int tx = threadIdx.x & 31, ty = threadIdx.x >> 5;
    for (int kk = ty; kk < 32; kk += 8)
        tile[kk][tx] = W[(size_t)(k0 + kk) * N + n0 + tx];
    __syncthreads();

    const int nn = tx;
    const int oc = ty;            // 0..7
    const int o2 = oc & 3;        // k-octet
    const bool isLo = (oc >> 2) != 0;
    const int kblk = (k0 >> 4) + (o2 >> 1);
    const int lane_in_packet = nn + 32 * (o2 & 1);

    frag_u f;
#pragma unroll
    for (int j = 0; j < 8; ++j) {
        float wv = tile[o2 * 8 + j][nn];
        bf16_t h = (bf16_t)wv;                          // original hi rounding
        bf16_t l = (bf16_t)(wv - (float)h);             // original lo rounding
        f.v[j] = isLo ? (bf16_t)(2.0f * (float)l)       // exact doubling
                      : (bf16_t)(2.0f * (float)h);
    }
    bf16_t* dst = (isLo ? lo : hi)
        + ((size_t)((n0 + nn) >> 5) * NKB + kblk) * 512 + lane_in_packet * 8;
    *(bf16x8*)dst = f.v;
}

// ---------------------------------------------------------------------------
// Fused MFMA GEMM + multistep LIF. R31: bf16-A full-LDS staging (ring-4,
// 12KB slabs, 3 VMEM ops/wave-step), no in-loop expansion, counted waits,
// fused mean (LAST).
// ---------------------------------------------------------------------------
template <int K, bool LAST>
__global__ __launch_bounds__(256, 4)
void gemm_lif_mfma(const uint8_t* __restrict__ Abytes,
                   const bf16_t* __restrict__ Bh,
                   const bf16_t* __restrict__ Bl,
                   const float* __restrict__ bias,
                   uint8_t* __restrict__ Sbytes,
                   float* __restrict__ Out,
                   int M, int N)
{
    constexpr int NKB = K >> 4;                 // 8 or 64 (>= 4, even)
    constexpr int SLAB = 12288;                 // A 8KB + B 4KB per kb
    // Slab: [A m0 4KB | A m1 4KB | B n0 hi 1KB | B n0 lo | B n1 hi | B n1 lo]
    __shared__ __align__(16) uint8_t ldsR[4][SLAB];      // 48KB ring
    __shared__ __align__(8) unsigned short sh[4][256];   // epilogue, per-wave

    const int tid = threadIdx.x;
    const int lane = tid & 63;
    const int wid = tid >> 6;
    const int l31 = lane & 31;
    const int half = lane >> 5;

    // XCD-locality swizzle (R18): XCD x owns m_t in [x*16, x*16+16);
    // walk nh(2) x mloc(16) x n8(8). Bijective.
    const int bid = blockIdx.x;
    const int xcd = bid & 7;
    const int j   = bid >> 3;                   // 0..255
    const int nh   = j >> 7;                    // 0..1
    const int r    = j & 127;
    const int mloc = r >> 3;                    // 0..15
    const int n_t  = nh * 8 + (r & 7);          // 0..15
    const int m_t  = xcd * 16 + mloc;           // 0..127

    const int m0 = m_t * 64, n0 = n_t * 64;
    const int wave_m = (wid & 1) * 32;
    const int wave_n = (wid >> 1) * 32;
    const int m_blk = (m0 + wave_m) >> 5;

    // ---- staging assignment: 12 chunks of 1KB per kb; wave wid stages
    //      chunks 3*wid .. 3*wid+2. c<8: A (m_local=c>>2, t=c&3);
    //      c>=8: B (n_local=(c-8)>>1, plane=(c-8)&1). All wave-uniform.
    const uint8_t* csrc[3];
    uint32_t cstride[3], cdst[3];
#pragma unroll
    for (int i = 0; i < 3; ++i) {
        int c = wid * 3 + i;
        if (c < 8) {
            int ml = c >> 2, tt = c & 3;
            csrc[i] = Abytes + ((size_t)((m0 >> 5) + ml)) * NKB * 4096
                      + tt * 1024 + (lane << 4);
            cstride[i] = 4096;
            cdst[i] = ml * 4096 + tt * 1024;
        } else {
            int cb = c - 8, nl = cb >> 1, pl = cb & 1;
            csrc[i] = (const uint8_t*)(pl ? Bl : Bh)
                      + ((size_t)((n0 >> 5) + nl)) * NKB * 1024 + (lane << 4);
            cstride[i] = 1024;
            cdst[i] = 8192 + nl * 2048 + pl * 1024;
        }
    }
    uint8_t* ringBase = &ldsR[0][0];

    // ---- consumer fragment addresses ----
    // A: slot + (wid&1)*4096 + t*1024 + half*512 + l31*16  (bf16x8 per t)
    // B: slot + 8192 + (wid>>1)*2048 (+1024 lo) + lane*16  (bf16x8)
    const int aRdOff = (wid & 1) * 4096 + half * 512 + l31 * 16;
    const int bRdOff = 8192 + ((wid >> 1) << 11) + (lane << 4);

    f32x16 acc[TSTEPS];
#pragma unroll
    for (int t = 0; t < TSTEPS; ++t)
        for (int rr = 0; rr < 16; ++rr) acc[t][rr] = 0.0f;

    bf16x8 af0, af1, af2, af3, cfh, cfl;

#define STAGE3(kb_, sl_) {                                                    \
    _Pragma("unroll")                                                         \
    for (int i = 0; i < 3; ++i) {                                             \
        __builtin_amdgcn_global_load_lds(                                     \
            (const __attribute__((address_space(1))) uint32_t*)               \
                (csrc[i] + (size_t)(kb_) * cstride[i]),                       \
            (__attribute__((address_space(3))) uint32_t*)                     \
                (ringBase + (sl_) * SLAB + cdst[i]),                          \
            16, 0, 0);                                                        \
    }                                                                         \
    }

#define FRAGRD(sl_) {                                                        \
        const uint8_t* sb = ringBase + (sl_) * SLAB;                         \
        af0 = *(const bf16x8*)(sb + aRdOff);                                 \
        af1 = *(const bf16x8*)(sb + aRdOff + 1024);                          \
        af2 = *(const bf16x8*)(sb + aRdOff + 2048);                          \
        af3 = *(const bf16x8*)(sb + aRdOff + 3072);                          \
        cfh = *(const bf16x8*)(sb + bRdOff);                                 \
        cfl = *(const bf16x8*)(sb + bRdOff + 1024);                          \
    }

#define MFMAS() {                                                            \
        acc[0] = __builtin_amdgcn_mfma_f32_32x32x16_bf16(af0, cfh, acc[0], 0, 0, 0); \
        acc[1] = __builtin_amdgcn_mfma_f32_32x32x16_bf16(af1, cfh, acc[1], 0, 0, 0); \
        acc[2] = __builtin_amdgcn_mfma_f32_32x32x16_bf16(af2, cfh, acc[2], 0, 0, 0); \
        acc[3] = __builtin_amdgcn_mfma_f32_32x32x16_bf16(af3, cfh, acc[3], 0, 0, 0); \
        acc[0] = __builtin_amdgcn_mfma_f32_32x32x16_bf16(af0, cfl, acc[0], 0, 0, 0); \
        acc[1] = __builtin_amdgcn_mfma_f32_32x32x16_bf16(af1, cfl, acc[1], 0, 0, 0); \
        acc[2] = __builtin_amdgcn_mfma_f32_32x32x16_bf16(af2, cfl, acc[2], 0, 0, 0); \
        acc[3] = __builtin_amdgcn_mfma_f32_32x32x16_bf16(af3, cfl, acc[3], 0, 0, 0); \
    }

    // Prologue: stage kb 0,1 (slots 0,1); drain stage(0); read frags(0).
    STAGE3(0, 0);
    STAGE3(1, 1);
    __builtin_amdgcn_s_waitcnt(WT_VM3);      // drains stage(0) (3 newer)
    asm volatile("" ::: "memory");
    __builtin_amdgcn_s_barrier();
    asm volatile("" ::: "memory");
    FRAGRD(0);

    // Steady state: step kb computes kb (frags pre-read), stages kb+2 into
    // slot (kb+2)&3, publishes kb+1.
    // vmcnt(3): outstanding = stage(kb+1) 3 + stage(kb+2) 3 -> drains
    // stage(kb+1) (one full step of latency cover). lgkm(0): drains the
    // hoisted frag reads for kb. Ring-4 reuse: slot (kb+2)&3 held kb-2,
    // drained two barriers before this stage issues.
    for (int kb = 0; kb < NKB - 2; ++kb) {
        STAGE3(kb + 2, (kb + 2) & 3);
        __builtin_amdgcn_s_waitcnt(WT_VM3_LG0);
        asm volatile("" ::: "memory");
        MFMAS();
        __builtin_amdgcn_s_barrier();
        asm volatile("" ::: "memory");
        FRAGRD((kb + 1) & 3);
    }
    // Step NKB-2: nothing to stage; drain stage(NKB-1) + frag reads.
    __builtin_amdgcn_s_waitcnt(WT_VM0_LG0);
    asm volatile("" ::: "memory");
    MFMAS();
    __builtin_amdgcn_s_barrier();
    asm volatile("" ::: "memory");
    FRAGRD((NKB - 1) & 3);
    // Step NKB-1: final.
    __builtin_amdgcn_s_waitcnt(WT_LG0);
    asm volatile("" ::: "memory");
    MFMAS();

#undef MFMAS
#undef FRAGRD
#undef STAGE3

    // --- LIF epilogue: t-scan in registers (XLA-exact arithmetic) ---
    const float bv = bias[n0 + wave_n + l31];
    f32x16 vmem;
#pragma unroll
    for (int rr = 0; rr < 16; ++rr) vmem[rr] = 0.0f;
    uint64_t bits = 0ull;
    unsigned short* myt = &sh[wid][0];          // [row][kb][t] = [32][2][4]

    const int NKBo = N >> 4;
    const int kbase = (n0 + wave_n) >> 4;

    for (int t = 0; t < TSTEPS; ++t) {
#pragma unroll
        for (int rr = 0; rr < 16; ++rr) {
            float y = __fadd_rn(acc[t][rr], bv);
            float vv = vmem[rr];
            vv = __fadd_rn(vv, __fmul_rn(__fsub_rn(y, vv), 0.5f));
            bool sp = (vv >= 1.0f);
            vmem[rr] = sp ? 0.0f : vv;
            if (LAST) {
                bits |= sp ? (1ull << (rr * 4 + t)) : 0ull;
            } else {
                unsigned long long b = __ballot(sp);
                if (l31 == 0) {
                    uint32_t hb = (uint32_t)(b >> (half * 32));
                    int rowi = (rr & 3) + 8 * (rr >> 2) + 4 * half;
                    myt[(rowi * 2 + 0) * 4 + t] = (unsigned short)hb;
                    myt[(rowi * 2 + 1) * 4 + t] = (unsigned short)(hb >> 16);
                }
            }
        }
    }

    if (LAST) {
        // Out writes + fused mean-over-L. All values multiples of 2^-11,
        // totals <= 1 -> fp32 atomics exact and order-independent.
        float psum = 0.0f;
#pragma unroll
        for (int rr = 0; rr < 16; ++rr) {
            int m_r = (rr & 3) + 8 * (rr >> 2) + 4 * half;
            int m = m0 + wave_m + m_r;
            int n = n0 + wave_n + l31;
            int cnt = __popc((unsigned)((bits >> (rr * 4)) & 0xFull));
            float val = 0.25f * (float)cnt;
            Out[(size_t)m * N + n] = val;
            psum += val;                       // exact: multiples of 0.25
        }
        // combine the two halves (same n, other 16 m's of the 32-row blk)
        psum += __shfl_xor(psum, 32, 64);
        if (half == 0) {
            float* out2 = Out + (size_t)M * N;
            int b = m0 >> 9;                   // m0 multiple of 64; L = 512
            int n = n0 + wave_n + l31;
            atomicAdd(out2 + (size_t)b * N + n, psum * (1.0f / 512.0f));
        }
    } else {
        // Emit next-stage A as bf16 packets [t][half][row][16B]
        // (0x0000 / 0x3F00). Thread (l31=row, half=kb-within-pair).
        const ushort4v pk = *(const ushort4v*)&myt[(l31 * 2 + half) * 4];
        uint8_t* pkt0 = Sbytes
            + ((size_t)m_blk * NKBo + kbase + half) * 4096;
#pragma unroll
        for (int t = 0; t < TSTEPS; ++t) {
            uint32_t m16 = pk[t];
            uint32_t d[8];
#pragma unroll
            for (int jj = 0; jj < 8; ++jj) {
                uint32_t x2 = (m16 >> (2 * jj)) & 3u;
                d[jj] = ((x2 | (x2 << 15)) & 0x00010001u) * 0x3F00u;
            }
            uint4 o0; o0.x = d[0]; o0.y = d[1]; o0.z = d[2]; o0.w = d[3];
            uint4 o1; o1.x = d[4]; o1.y = d[5]; o1.z = d[6]; o1.w = d[7];
            *(uint4*)(pkt0 + (size_t)t * 1024 + l31 * 16)       = o0;
            *(uint4*)(pkt0 + (size_t)t * 1024 + 512 + l31 * 16) = o1;
        }
    }
}

// ---------------------------------------------------------------------------
// Zero out2 (graph-capture-safe replacement for hipMemsetAsync).
// ---------------------------------------------------------------------------
__global__ void zero_out2(float* __restrict__ out2, int n)
{
    int i = blockIdx.x * blockDim.x + threadIdx.x;
    if (i < n) out2[i] = 0.0f;
}

// ---------------------------------------------------------------------------
extern "C" void kernel_launch(void* const* d_in, const int* in_sizes, int n_in,
                              void* d_out, int out_size, void* d_ws, size_t ws_size,
                              hipStream_t stream)
{
    const float* inputs  = (const float*)d_in[0];  // [16,512,128]
    const float* enc_W   = (const float*)d_in[1];  // [128,1024]
    const float* enc_b   = (const float*)d_in[2];  // [1024]
    const float* W_cells = (const float*)d_in[3];  // [2,1024,1024]
    const float* b_cells = (const float*)d_in[4];  // [2,1024]

    const int B = 16, L = 512, C = 128, D = 1024;
    const int M = B * L;  // 8192

    // ws: W1h/l 0.5MB | W2h/l 4MB | W3h/l 4MB | h0 64MB | h1 64MB
    // s1 (8MB bf16 packets) ALIASED into h1: fully consumed by GEMM1 before
    // GEMM2 writes h1 (same stream, ordered).
    char* ws = (char*)d_ws;
    size_t off = 0;
    bf16_t* W1h = (bf16_t*)(ws + off); off += (size_t)C * D * 2;
    bf16_t* W1l = (bf16_t*)(ws + off); off += (size_t)C * D * 2;
    bf16_t* W2h = (bf16_t*)(ws + off); off += (size_t)D * D * 2;
    bf16_t* W2l = (bf16_t*)(ws + off); off += (size_t)D * D * 2;
    bf16_t* W3h = (bf16_t*)(ws + off); off += (size_t)D * D * 2;
    bf16_t* W3l = (bf16_t*)(ws + off); off += (size_t)D * D * 2;
    uint8_t* h0 = (uint8_t*)(ws + off);
    off += (size_t)(M / 32) * (D / 16) * 4096;   // 64 MB
    uint8_t* h1 = (uint8_t*)(ws + off);
    uint8_t* s1 = h1;                            // aliased (see above)

    float* out  = (float*)d_out;          // [M, D]
    float* out2 = out + (size_t)M * D;    // [B, D]

    split_transpose_all<<<dim3(32, 32, 3), 256, 0, stream>>>(
        enc_W, W_cells, W1h, W1l, W2h, W2l, W3h, W3l);

    spike_encode_bf16<<<256, 256, 0, stream>>>(inputs, s1);

    zero_out2<<<(B * D + 255) / 256, 256, 0, stream>>>(out2, B * D);

    const int nblocks = (M / 64) * (D / 64);   // 2048
    gemm_lif_mfma<128, false><<<nblocks, 256, 0, stream>>>(
        s1, W1h, W1l, enc_b, h0, nullptr, M, D);
    gemm_lif_mfma<1024, false><<<nblocks, 256, 0, stream>>>(
        h0, W2h, W2l, b_cells, h1, nullptr, M, D);
    gemm_lif_mfma<1024, true><<<nblocks, 256, 0, stream>>>(
        h1, W3h, W3l, b_cells + D, nullptr, out, M, D);
}